// Round 2
// 408.959 us; speedup vs baseline: 1.0358x; 1.0358x over previous
//
#include <hip/hip_runtime.h>

// Haar wavelet transform along seq axis:
//   x: (64, 4096, 256) fp32  ->  out: (64, 2048, 512) fp32
//   out[b, t, 2f]   = (x[b,2t,f] + x[b,2t+1,f]) * INV_SQRT2
//   out[b, t, 2f+1] = (x[b,2t,f] - x[b,2t+1,f]) * INV_SQRT2
//
// pair index p = b*2048 + t; row0 = x + p*512, row1 = row0 + 256,
// out row = out + p*512 (512 floats).
//
// Mapping (R2, kept): 64 lanes per out row. Lane l stores out floats
// [4l,4l+4) and [256+4l,256+4l+4) -> each store instruction is a contiguous
// 1 KiB wave region. Inputs are four float2 loads (f=2l,2l+1 and
// f=128+2l,128+2l+1), each wave-contiguous 512 B.
//
// R4 = R3 resubmit (R3 bench was an infra failure, no data): single
// variable change vs R2 = non-temporal hints on every load/store.
// Zero-reuse stream of 537 MB total; in+out (536 MB) exceeds L3 (256 MB),
// so cache allocation is pure overhead; nt skips L2/L3 allocation.
// Evidence kernel is near roofline already: rocprof top-5 are all ~165 us
// harness fills (kernel dispatch < 162 us); dur_us 423 = ~2x165 fill
// + ~93 us kernel; mixed-stream floor ~88-91 us at ~6 TB/s.

#define INV_SQRT2 0.70710678118654752440f

typedef float f32x2 __attribute__((ext_vector_type(2)));
typedef float f32x4 __attribute__((ext_vector_type(4)));

__global__ __launch_bounds__(256) void W_Transform_45938970198411_kernel(
        const float* __restrict__ x, float* __restrict__ out) {
    const unsigned int i = blockIdx.x * blockDim.x + threadIdx.x;  // [0, 8388608)
    const unsigned int l = i & 63u;   // lane-task within one output row
    const unsigned int p = i >> 6;    // pair-row index

    const float* __restrict__ r0 = x + (size_t)p * 512;        // row 2t
    const float* __restrict__ r1 = r0 + 256;                   // row 2t+1

    const f32x2 a0 = __builtin_nontemporal_load((const f32x2*)(r0 + 2 * l));
    const f32x2 b0 = __builtin_nontemporal_load((const f32x2*)(r1 + 2 * l));
    const f32x2 a1 = __builtin_nontemporal_load((const f32x2*)(r0 + 128 + 2 * l));
    const f32x2 b1 = __builtin_nontemporal_load((const f32x2*)(r1 + 128 + 2 * l));

    f32x4 o0, o1;
    o0.x = (a0.x + b0.x) * INV_SQRT2;
    o0.y = (a0.x - b0.x) * INV_SQRT2;
    o0.z = (a0.y + b0.y) * INV_SQRT2;
    o0.w = (a0.y - b0.y) * INV_SQRT2;
    o1.x = (a1.x + b1.x) * INV_SQRT2;
    o1.y = (a1.x - b1.x) * INV_SQRT2;
    o1.z = (a1.y + b1.y) * INV_SQRT2;
    o1.w = (a1.y - b1.y) * INV_SQRT2;

    float* ob = out + (size_t)p * 512;
    __builtin_nontemporal_store(o0, (f32x4*)(ob + 4 * l));        // contiguous 1 KiB
    __builtin_nontemporal_store(o1, (f32x4*)(ob + 256 + 4 * l));  // contiguous 1 KiB
}

extern "C" void kernel_launch(void* const* d_in, const int* in_sizes, int n_in,
                              void* d_out, int out_size, void* d_ws, size_t ws_size,
                              hipStream_t stream) {
    const float* x = (const float*)d_in[0];
    float* out = (float*)d_out;
    // total threads = 131072 rows * 64 lanes = 8,388,608 -> 32768 blocks of 256
    const int n_threads = 64 * 2048 * 64;
    const int block = 256;
    const int grid = n_threads / block;
    W_Transform_45938970198411_kernel<<<grid, block, 0, stream>>>(x, out);
}